// Round 8
// baseline (218.381 us; speedup 1.0000x reference)
//
#include <hip/hip_runtime.h>
#include <hip/hip_bf16.h>

typedef __bf16 bf16_t;
typedef bf16_t bf16x8 __attribute__((ext_vector_type(8)));
typedef float floatx4 __attribute__((ext_vector_type(4)));
typedef float floatx2 __attribute__((ext_vector_type(2)));

#define N_NODES 100000
#define N_EDGES 1000000
#define N_TILES 6250

// PQ8 row layout (256 B per node): byte b = h*128 + l15*8 + j  holds fp8 of
// column  h*128 + j*16 + l15   (h = half, l15 = 0..15, j = 0..7).
// Edge kernel lane lg reads bytes lg*8..lg*8+7 of a half -> channels j*16+lg;
// identical mapping for p-half and q-half, wabs permuted to match.

// ---------------- kernel 1: prep (parallelized) ----------------
__global__ __launch_bounds__(256) void k_prep(const float* __restrict__ W1,
                                              const float* __restrict__ b1,
                                              const float* __restrict__ alpha,
                                              const float* __restrict__ W2,
                                              const float* __restrict__ b2,
                                              bf16_t* __restrict__ WT,
                                              float* __restrict__ wabsp,
                                              float* __restrict__ u1g,
                                              float* __restrict__ u2g,
                                              float* __restrict__ constg,
                                              float* __restrict__ out) {
    const int t = threadIdx.x;
    if (blockIdx.x < 128) {
        int i = blockIdx.x * 256 + t;           // 32768 total
        int n = i >> 7;
        int k = i & 127;
        float v = (n < 128) ? W1[k * 128 + n] : W1[(k + 128) * 128 + (n - 128)];
        WT[i] = (bf16_t)v;
        return;
    }
    // block 128: small vectors, fully parallel
    __shared__ float w1L[128];
    __shared__ float part1[256];
    __shared__ float part2[256];
    if (t < 128) {
        float wd = W2[2 * t + 1] - W2[2 * t];
        float al = alpha[t];
        w1L[t] = wd * (1.f + al) * 0.5f;
        int c = (t & 7) * 16 + (t >> 3);          // permuted channel
        float wdc = W2[2 * c + 1] - W2[2 * c];
        wabsp[t] = wdc * (1.f - alpha[c]) * 0.5f;
    }
    __syncthreads();
    {   // u1[o] = sum_j W1[o,j] w1[j]; u2[o] = sum_j W1[o+128,j] w1[j]
        int o = t >> 1, hf = t & 1;
        const float* r1 = W1 + (size_t)o * 128 + hf * 64;
        const float* r2 = W1 + (size_t)(o + 128) * 128 + hf * 64;
        const float* wl = w1L + hf * 64;
        float a1 = 0.f, a2 = 0.f;
#pragma unroll 8
        for (int j = 0; j < 64; ++j) {
            a1 = fmaf(r1[j], wl[j], a1);
            a2 = fmaf(r2[j], wl[j], a2);
        }
        part1[t] = a1;
        part2[t] = a2;
    }
    __syncthreads();
    if (t < 128) {
        u1g[t] = part1[2 * t] + part1[2 * t + 1];
        u2g[t] = part2[2 * t] + part2[2 * t + 1];
    }
    if (t < 64) {   // CONST = sum w1L*b1 + (b2[1]-b2[0]), wave-reduced
        float c = fmaf(w1L[t], b1[t], w1L[t + 64] * b1[t + 64]);
#pragma unroll
        for (int m = 32; m >= 1; m >>= 1) c += __shfl_xor(c, m, 64);
        if (t == 0) { *constg = c + (b2[1] - b2[0]); out[0] = 0.f; }
    }
}

// ---------------- kernel 2: persistent-wave GEMM, B resident, pipelined ----
__global__ __launch_bounds__(256) void k_gemm(const float* __restrict__ F,     // [100000,128]
                                              const bf16_t* __restrict__ WT,   // [256,128]
                                              const float* __restrict__ b1,
                                              const float* __restrict__ u1g,
                                              const float* __restrict__ u2g,
                                              const int* __restrict__ label,
                                              unsigned char* __restrict__ PQ8,
                                              float4* __restrict__ aux_g) {
    const int w = threadIdx.x >> 6, lane = threadIdx.x & 63;
    const int l15 = lane & 15, quad = lane >> 4;
    const int h = w >> 1, jb = (w & 1) * 4;

    // resident B fragments: B[n = w*64 + nt*16 + l15][k = s*32 + quad*8 ..]
    bf16x8 Bf[4][4];
    const bf16_t* wbase = WT + (size_t)(w * 64 + l15) * 128 + quad * 8;
#pragma unroll
    for (int s = 0; s < 4; ++s)
#pragma unroll
        for (int nt = 0; nt < 4; ++nt)
            Bf[s][nt] = *(const bf16x8*)(wbase + (size_t)nt * 2048 + s * 32);

    float bv[4];
#pragma unroll
    for (int nt = 0; nt < 4; ++nt)
        bv[nt] = (h == 0) ? b1[(jb + nt) * 16 + l15] : 0.f;

    int tile = blockIdx.x;
    float4 fa[4], fb[4];
    if (tile < N_TILES) {
        const float4* Ar = (const float4*)(F + (size_t)(tile * 16 + l15) * 128 + quad * 8);
#pragma unroll
        for (int s = 0; s < 4; ++s) { fa[s] = Ar[s * 8]; fb[s] = Ar[s * 8 + 1]; }
    }

    while (tile < N_TILES) {
        const int next = tile + gridDim.x;
        const int m0 = tile * 16;

        // convert to bf16 fragments (fa/fb die here)
        bf16x8 Af[4];
#pragma unroll
        for (int s = 0; s < 4; ++s) {
            bf16x8 v;
            v[0] = (bf16_t)fa[s].x; v[1] = (bf16_t)fa[s].y;
            v[2] = (bf16_t)fa[s].z; v[3] = (bf16_t)fa[s].w;
            v[4] = (bf16_t)fb[s].x; v[5] = (bf16_t)fb[s].y;
            v[6] = (bf16_t)fb[s].z; v[7] = (bf16_t)fb[s].w;
            Af[s] = v;
        }
        // prefetch next tile's A under this tile's compute
        if (next < N_TILES) {
            const float4* Ar = (const float4*)(F + (size_t)(next * 16 + l15) * 128 + quad * 8);
#pragma unroll
            for (int s = 0; s < 4; ++s) { fa[s] = Ar[s * 8]; fb[s] = Ar[s * 8 + 1]; }
        }

        // aux (wave 0 only), from bf16 fragments
        if (w == 0) {
            float s1 = 0.f, s2 = 0.f;
#pragma unroll
            for (int s = 0; s < 4; ++s) {
                const float* u1p = u1g + s * 32 + quad * 8;
                const float* u2p = u2g + s * 32 + quad * 8;
                bf16x8 aw = Af[s];
#pragma unroll
                for (int j = 0; j < 8; ++j) {
                    float fv = (float)aw[j];
                    s1 = fmaf(fv, u1p[j], s1);
                    s2 = fmaf(fv, u2p[j], s2);
                }
            }
            s1 += __shfl_xor(s1, 16, 64); s1 += __shfl_xor(s1, 32, 64);
            s2 += __shfl_xor(s2, 16, 64); s2 += __shfl_xor(s2, 32, 64);
            if (quad == 0) {
                int grow = m0 + l15;
                float4 av = {s1, s2, __int_as_float(label[grow]), 0.f};
                aux_g[grow] = av;
            }
        }

        floatx4 acc[4] = {};
#pragma unroll
        for (int s = 0; s < 4; ++s)
#pragma unroll
            for (int nt = 0; nt < 4; ++nt)
                acc[nt] = __builtin_amdgcn_mfma_f32_16x16x32_bf16(Af[s], Bf[s][nt], acc[nt], 0, 0, 0);

        // epilogue: row = m0 + quad*4 + r, cols (jb+nt)*16 + l15 of half h
#pragma unroll
        for (int r = 0; r < 4; ++r) {
            int grow = m0 + quad * 4 + r;
            unsigned int pk = 0;
            pk = __builtin_amdgcn_cvt_pk_fp8_f32(acc[0][r] + bv[0], acc[1][r] + bv[1], pk, false);
            pk = __builtin_amdgcn_cvt_pk_fp8_f32(acc[2][r] + bv[2], acc[3][r] + bv[3], pk, true);
            *(unsigned int*)(PQ8 + (size_t)grow * 256 + h * 128 + l15 * 8 + jb) = pk;
        }
        tile = next;
    }
}

// ---------------- kernel 3: per-edge loss, 16 lanes/edge, 8-edge ILP -------
__global__ __launch_bounds__(256) void k_edge_loss(const unsigned char* __restrict__ PQ8,
                                                   const float4* __restrict__ aux,
                                                   const float* __restrict__ wabsp,
                                                   const float* __restrict__ constg,
                                                   const int* __restrict__ row,
                                                   const int* __restrict__ col,
                                                   float* __restrict__ out) {
    const int lg = threadIdx.x & 15;
    const int group = (blockIdx.x * blockDim.x + threadIdx.x) >> 4;
    const int ng = (gridDim.x * blockDim.x) >> 4;
    const int ch = lg * 8;

    float wabs[8];
#pragma unroll
    for (int j = 0; j < 8; ++j) wabs[j] = wabsp[ch + j];
    const float CB = *constg;

    float acc = 0.f;
    for (int e = group; e < N_EDGES; e += 8 * ng) {
        int r[8], c[8];
#pragma unroll
        for (int k = 0; k < 8; ++k) {
            int ee = e + k * ng;
            int es = (ee < N_EDGES) ? ee : e;
            r[k] = row[es]; c[k] = col[es];
        }
        uint2 p[8], q[8];
#pragma unroll
        for (int k = 0; k < 8; ++k) {
            p[k] = *(const uint2*)(PQ8 + (size_t)r[k] * 256 + ch);
            q[k] = *(const uint2*)(PQ8 + (size_t)c[k] * 256 + 128 + ch);
        }
        // per-lane aux: lanes 0-7 take edge lg's row-aux, lanes 8-15 edge (lg-8)'s col-aux
        int ee2 = e + (lg & 7) * ng;
        int es2 = (ee2 < N_EDGES) ? ee2 : e;
        const int* ibase = (lg < 8) ? row : col;
        float4 a = aux[ibase[es2]];

        float sab[8] = {0.f, 0.f, 0.f, 0.f, 0.f, 0.f, 0.f, 0.f};
#pragma unroll
        for (int k = 0; k < 8; ++k) {
            floatx2 p01 = __builtin_amdgcn_cvt_pk_f32_fp8((int)p[k].x, false);
            floatx2 p23 = __builtin_amdgcn_cvt_pk_f32_fp8((int)p[k].x, true);
            floatx2 p45 = __builtin_amdgcn_cvt_pk_f32_fp8((int)p[k].y, false);
            floatx2 p67 = __builtin_amdgcn_cvt_pk_f32_fp8((int)p[k].y, true);
            floatx2 q01 = __builtin_amdgcn_cvt_pk_f32_fp8((int)q[k].x, false);
            floatx2 q23 = __builtin_amdgcn_cvt_pk_f32_fp8((int)q[k].x, true);
            floatx2 q45 = __builtin_amdgcn_cvt_pk_f32_fp8((int)q[k].y, false);
            floatx2 q67 = __builtin_amdgcn_cvt_pk_f32_fp8((int)q[k].y, true);
            floatx2 h01 = p01 + q01;
            floatx2 h23 = p23 + q23;
            floatx2 h45 = p45 + q45;
            floatx2 h67 = p67 + q67;
            float s = sab[k];
            s = fmaf(fabsf(h01[0]), wabs[0], s);
            s = fmaf(fabsf(h01[1]), wabs[1], s);
            s = fmaf(fabsf(h23[0]), wabs[2], s);
            s = fmaf(fabsf(h23[1]), wabs[3], s);
            s = fmaf(fabsf(h45[0]), wabs[4], s);
            s = fmaf(fabsf(h45[1]), wabs[5], s);
            s = fmaf(fabsf(h67[0]), wabs[6], s);
            s = fmaf(fabsf(h67[1]), wabs[7], s);
            sab[k] = s;
        }
#pragma unroll
        for (int m = 8; m >= 1; m >>= 1) {
#pragma unroll
            for (int k = 0; k < 8; ++k) sab[k] += __shfl_xor(sab[k], m, 16);
        }
        // lanes 0-7 finish edge lg in parallel
        float s2o = __shfl(a.y, (lg + 8) & 15, 16);
        float lzc = __shfl(a.z, (lg + 8) & 15, 16);
        float mysab = sab[0];
#pragma unroll
        for (int k = 1; k < 8; ++k) mysab = (lg == k) ? sab[k] : mysab;
        float D = a.x + s2o + CB + mysab;
        float sgn = (__float_as_int(a.z) == __float_as_int(lzc)) ? -D : D;
        float loss = fmaxf(sgn, 0.f) + __logf(1.f + __expf(-fabsf(sgn)));
        bool vld = (lg < 8) && (e + lg * ng < N_EDGES);
        acc += vld ? loss : 0.f;
    }
#pragma unroll
    for (int m = 32; m >= 1; m >>= 1) acc += __shfl_xor(acc, m, 64);
    __shared__ float sdata[4];
    int lane = threadIdx.x & 63;
    int wv = threadIdx.x >> 6;
    if (lane == 0) sdata[wv] = acc;
    __syncthreads();
    if (threadIdx.x == 0) {
        float s = (sdata[0] + sdata[1]) + (sdata[2] + sdata[3]);
        atomicAdd(out, s * (1.f / (float)N_EDGES));
    }
}

extern "C" void kernel_launch(void* const* d_in, const int* in_sizes, int n_in,
                              void* d_out, int out_size, void* d_ws, size_t ws_size,
                              hipStream_t stream) {
    const float* feature = (const float*)d_in[0];   // [100000,128]
    const float* W1      = (const float*)d_in[1];   // [256,128]
    const float* b1      = (const float*)d_in[2];   // [128]
    const float* alpha   = (const float*)d_in[3];   // [128]
    const float* W2      = (const float*)d_in[4];   // [128,2]
    const float* b2      = (const float*)d_in[5];   // [2]
    const int*   row     = (const int*)d_in[6];     // [1M]
    const int*   col     = (const int*)d_in[7];     // [1M]
    const int*   label   = (const int*)d_in[8];     // [100000]
    float* out = (float*)d_out;

    char* ws = (char*)d_ws;
    unsigned char* PQ8 = (unsigned char*)(ws);      // 25,600,000 B
    float4* aux  = (float4*)(ws + 25600000);        // 1,600,000 B
    bf16_t* WT   = (bf16_t*)(ws + 27200000);        // 65,536 B
    float* wabsp = (float*)(ws + 27265536);         // 512 B
    float* u1g   = (float*)(ws + 27266048);         // 512 B
    float* u2g   = (float*)(ws + 27266560);         // 512 B
    float* constg= (float*)(ws + 27267072);         // 4 B

    k_prep<<<129, 256, 0, stream>>>(W1, b1, alpha, W2, b2, WT, wabsp, u1g, u2g,
                                    constg, out);
    k_gemm<<<1024, 256, 0, stream>>>(feature, WT, b1, u1g, u2g, label, PQ8, aux);
    k_edge_loss<<<4096, 256, 0, stream>>>(PQ8, aux, wabsp, constg, row, col, out);
}

// Round 10
// 197.988 us; speedup vs baseline: 1.1030x; 1.1030x over previous
//
#include <hip/hip_runtime.h>
#include <hip/hip_bf16.h>

typedef __bf16 bf16_t;
typedef bf16_t bf16x8 __attribute__((ext_vector_type(8)));
typedef float floatx4 __attribute__((ext_vector_type(4)));
typedef float floatx2 __attribute__((ext_vector_type(2)));

#define N_NODES 100000
#define N_EDGES 1000000

// PQ8 layout (256 B/node): within half h, byte b (0..127) holds fp8 of
// channel col(b) = (b & 64) + (b & 3)*16 + ((b >> 2) & 15).
// Gemm wave (h, wq): stores dword at h*128 + wq*64 + l15*4 (bytes nt=0..3),
// so 16 lanes/quad write 64 contiguous bytes. Edge lane lg reads bytes
// lg*8..lg*8+7 of each half; wabsp[b] is permuted by col(b).

// ---------------- kernel 1: prep ----------------
__global__ __launch_bounds__(256) void k_prep(const float* __restrict__ W1,
                                              const float* __restrict__ b1,
                                              const float* __restrict__ alpha,
                                              const float* __restrict__ W2,
                                              const float* __restrict__ b2,
                                              bf16_t* __restrict__ WT,
                                              float* __restrict__ wabsp,
                                              float* __restrict__ w1g,
                                              float* __restrict__ constg,
                                              float* __restrict__ out) {
    const int t = threadIdx.x;
    if (blockIdx.x < 128) {
        // WT[n][k] = Wcat[k][n] bf16; Wcat[k,n] = n<128 ? W1[k,n] : W1[k+128,n-128]
        int i = blockIdx.x * 256 + t;
        int n = i >> 7, k = i & 127;
        float v = (n < 128) ? W1[k * 128 + n] : W1[(k + 128) * 128 + (n - 128)];
        WT[i] = (bf16_t)v;
        return;
    }
    __shared__ float w1L[128];
    if (t < 128) {
        float wd = W2[2 * t + 1] - W2[2 * t];
        float al = alpha[t];
        float w1v = wd * (1.f + al) * 0.5f;
        w1L[t] = w1v;
        w1g[t] = w1v;
        int col = (t & 64) + (t & 3) * 16 + ((t >> 2) & 15);   // byte->channel
        float wdc = W2[2 * col + 1] - W2[2 * col];
        wabsp[t] = wdc * (1.f - alpha[col]) * 0.5f;
    }
    __syncthreads();
    if (t < 64) {   // CONST = sum w1*b1 + (b2[1]-b2[0]), wave-reduced
        float c = fmaf(w1L[t], b1[t], w1L[t + 64] * b1[t + 64]);
#pragma unroll
        for (int m = 32; m >= 1; m >>= 1) c += __shfl_xor(c, m, 64);
        if (t == 0) { *constg = c + (b2[1] - b2[0]); out[0] = 0.f; }
    }
}

// ---------------- kernel 2: GEMM, B-half staged in LDS, 32 rows x 128 cols -
// grid = 6250: h = bid&1, m0 = (bid>>1)*32. Waves: rw = w>>1 picks row group,
// wq = w&1 picks 64-col block. Aux s1/s2 computed from accumulators.
__global__ __launch_bounds__(256) void k_gemm(const float* __restrict__ F,     // [100000,128]
                                              const bf16_t* __restrict__ WT,   // [256,128]
                                              const float* __restrict__ b1,
                                              const float* __restrict__ w1g,
                                              const int* __restrict__ label,
                                              unsigned char* __restrict__ PQ8,
                                              float* __restrict__ aux_g) {     // float4 slots
    __shared__ bf16x8 Bs[2048];      // 32 KB: half-B, swizzled chunks
    __shared__ float sP[4][16];
    const int t = threadIdx.x;
    const int h = blockIdx.x & 1;
    const int m0 = (blockIdx.x >> 1) * 32;

    // ---- stage B half h: rows c=0..127 of WT (n = h*128+c), 16 chunks/row,
    // chunk cc stored at c*16 + (cc ^ (c&15))  -> conflict-free frag reads
    const bf16x8* WT8 = (const bf16x8*)WT + (size_t)h * 2048;
#pragma unroll
    for (int j = 0; j < 8; ++j) {
        int chunk = j * 256 + t;        // 0..2047
        int c = chunk >> 4, cc = chunk & 15;
        Bs[c * 16 + (cc ^ (c & 15))] = WT8[chunk];
    }

    const int w = t >> 6, lane = t & 63;
    const int l15 = lane & 15, quad = lane >> 4;
    const int rw = w >> 1, wq = w & 1;

    // A loads (independent of LDS staging, issued before sync)
    const int arow = m0 + rw * 16 + l15;
    const float4* Ar = (const float4*)(F + (size_t)arow * 128 + quad * 8);
    float4 fa[4], fb[4];
#pragma unroll
    for (int s = 0; s < 4; ++s) { fa[s] = Ar[s * 8]; fb[s] = Ar[s * 8 + 1]; }

    float w1v[4], bv[4];
#pragma unroll
    for (int nt = 0; nt < 4; ++nt) {
        int c = wq * 64 + nt * 16 + l15;
        w1v[nt] = w1g[c];
        bv[nt] = (h == 0) ? b1[c] : 0.f;
    }

    bf16x8 Af[4];
#pragma unroll
    for (int s = 0; s < 4; ++s) {
        bf16x8 v;
        v[0] = (bf16_t)fa[s].x; v[1] = (bf16_t)fa[s].y;
        v[2] = (bf16_t)fa[s].z; v[3] = (bf16_t)fa[s].w;
        v[4] = (bf16_t)fb[s].x; v[5] = (bf16_t)fb[s].y;
        v[6] = (bf16_t)fb[s].z; v[7] = (bf16_t)fb[s].w;
        Af[s] = v;
    }
    __syncthreads();

    floatx4 acc[4] = {};
#pragma unroll
    for (int s = 0; s < 4; ++s) {
        bf16x8 Bf[4];
#pragma unroll
        for (int nt = 0; nt < 4; ++nt) {
            int c = wq * 64 + nt * 16 + l15;
            Bf[nt] = Bs[c * 16 + ((s * 4 + quad) ^ (c & 15))];
        }
#pragma unroll
        for (int nt = 0; nt < 4; ++nt)
            acc[nt] = __builtin_amdgcn_mfma_f32_16x16x32_bf16(Af[s], Bf[nt], acc[nt], 0, 0, 0);
    }

    // ---- aux partials: s_part(row) = sum_nt w1[c(nt)] * acc_raw[nt][row]
    float pr[4];
#pragma unroll
    for (int r = 0; r < 4; ++r) {
        float sv = 0.f;
#pragma unroll
        for (int nt = 0; nt < 4; ++nt) sv = fmaf(w1v[nt], acc[nt][r], sv);
#pragma unroll
        for (int m = 8; m >= 1; m >>= 1) sv += __shfl_xor(sv, m, 64);  // over l15
        pr[r] = sv;
    }
    if (l15 == 0) {
#pragma unroll
        for (int r = 0; r < 4; ++r) sP[w][quad * 4 + r] = pr[r];
    }

    // ---- epilogue: row g = m0 + rw*16 + quad*4 + r; 4 fp8 bytes -> 1 dword
#pragma unroll
    for (int r = 0; r < 4; ++r) {
        int g = m0 + rw * 16 + quad * 4 + r;
        unsigned int pk = 0;
        pk = __builtin_amdgcn_cvt_pk_fp8_f32(acc[0][r] + bv[0], acc[1][r] + bv[1], pk, false);
        pk = __builtin_amdgcn_cvt_pk_fp8_f32(acc[2][r] + bv[2], acc[3][r] + bv[3], pk, true);
        *(unsigned int*)(PQ8 + (size_t)g * 256 + h * 128 + wq * 64 + l15 * 4) = pk;
    }

    __syncthreads();
    if (t < 32) {
        int rw2 = t >> 4, ri = t & 15;
        float v = sP[rw2 * 2][ri] + sP[rw2 * 2 + 1][ri];
        int g = m0 + rw2 * 16 + ri;
        if (h == 0) {
            aux_g[(size_t)g * 4 + 0] = v;                      // s1
            ((int*)aux_g)[(size_t)g * 4 + 2] = label[g];       // label bits
        } else {
            aux_g[(size_t)g * 4 + 1] = v;                      // s2
        }
    }
}

// ---------------- kernel 3: per-edge loss, 16 lanes/edge, 8-edge ILP -------
__global__ __launch_bounds__(256) void k_edge_loss(const unsigned char* __restrict__ PQ8,
                                                   const float4* __restrict__ aux,
                                                   const float* __restrict__ wabsp,
                                                   const float* __restrict__ constg,
                                                   const int* __restrict__ row,
                                                   const int* __restrict__ col,
                                                   float* __restrict__ out) {
    const int lg = threadIdx.x & 15;
    const int group = (blockIdx.x * blockDim.x + threadIdx.x) >> 4;
    const int ng = (gridDim.x * blockDim.x) >> 4;
    const int ch = lg * 8;

    float wabs[8];
#pragma unroll
    for (int j = 0; j < 8; ++j) wabs[j] = wabsp[ch + j];
    const float CB = *constg;

    float acc = 0.f;
    for (int e = group; e < N_EDGES; e += 8 * ng) {
        int r[8], c[8];
#pragma unroll
        for (int k = 0; k < 8; ++k) {
            int ee = e + k * ng;
            int es = (ee < N_EDGES) ? ee : e;
            r[k] = row[es]; c[k] = col[es];
        }
        uint2 p[8], q[8];
#pragma unroll
        for (int k = 0; k < 8; ++k) {
            p[k] = *(const uint2*)(PQ8 + (size_t)r[k] * 256 + ch);
            q[k] = *(const uint2*)(PQ8 + (size_t)c[k] * 256 + 128 + ch);
        }
        int ee2 = e + (lg & 7) * ng;
        int es2 = (ee2 < N_EDGES) ? ee2 : e;
        const int* ibase = (lg < 8) ? row : col;
        float4 a = aux[ibase[es2]];

        float sab[8] = {0.f, 0.f, 0.f, 0.f, 0.f, 0.f, 0.f, 0.f};
#pragma unroll
        for (int k = 0; k < 8; ++k) {
            floatx2 p01 = __builtin_amdgcn_cvt_pk_f32_fp8((int)p[k].x, false);
            floatx2 p23 = __builtin_amdgcn_cvt_pk_f32_fp8((int)p[k].x, true);
            floatx2 p45 = __builtin_amdgcn_cvt_pk_f32_fp8((int)p[k].y, false);
            floatx2 p67 = __builtin_amdgcn_cvt_pk_f32_fp8((int)p[k].y, true);
            floatx2 q01 = __builtin_amdgcn_cvt_pk_f32_fp8((int)q[k].x, false);
            floatx2 q23 = __builtin_amdgcn_cvt_pk_f32_fp8((int)q[k].x, true);
            floatx2 q45 = __builtin_amdgcn_cvt_pk_f32_fp8((int)q[k].y, false);
            floatx2 q67 = __builtin_amdgcn_cvt_pk_f32_fp8((int)q[k].y, true);
            floatx2 h01 = p01 + q01;
            floatx2 h23 = p23 + q23;
            floatx2 h45 = p45 + q45;
            floatx2 h67 = p67 + q67;
            float s = sab[k];
            s = fmaf(fabsf(h01[0]), wabs[0], s);
            s = fmaf(fabsf(h01[1]), wabs[1], s);
            s = fmaf(fabsf(h23[0]), wabs[2], s);
            s = fmaf(fabsf(h23[1]), wabs[3], s);
            s = fmaf(fabsf(h45[0]), wabs[4], s);
            s = fmaf(fabsf(h45[1]), wabs[5], s);
            s = fmaf(fabsf(h67[0]), wabs[6], s);
            s = fmaf(fabsf(h67[1]), wabs[7], s);
            sab[k] = s;
        }
#pragma unroll
        for (int m = 8; m >= 1; m >>= 1) {
#pragma unroll
            for (int k = 0; k < 8; ++k) sab[k] += __shfl_xor(sab[k], m, 16);
        }
        float s2o = __shfl(a.y, (lg + 8) & 15, 16);
        float lzc = __shfl(a.z, (lg + 8) & 15, 16);
        float mysab = sab[0];
#pragma unroll
        for (int k = 1; k < 8; ++k) mysab = (lg == k) ? sab[k] : mysab;
        float D = a.x + s2o + CB + mysab;
        float sgn = (__float_as_int(a.z) == __float_as_int(lzc)) ? -D : D;
        float loss = fmaxf(sgn, 0.f) + __logf(1.f + __expf(-fabsf(sgn)));
        bool vld = (lg < 8) && (e + lg * ng < N_EDGES);
        acc += vld ? loss : 0.f;
    }
#pragma unroll
    for (int m = 32; m >= 1; m >>= 1) acc += __shfl_xor(acc, m, 64);
    __shared__ float sdata[4];
    int lane = threadIdx.x & 63;
    int wv = threadIdx.x >> 6;
    if (lane == 0) sdata[wv] = acc;
    __syncthreads();
    if (threadIdx.x == 0) {
        float s = (sdata[0] + sdata[1]) + (sdata[2] + sdata[3]);
        atomicAdd(out, s * (1.f / (float)N_EDGES));
    }
}

extern "C" void kernel_launch(void* const* d_in, const int* in_sizes, int n_in,
                              void* d_out, int out_size, void* d_ws, size_t ws_size,
                              hipStream_t stream) {
    const float* feature = (const float*)d_in[0];   // [100000,128]
    const float* W1      = (const float*)d_in[1];   // [256,128]
    const float* b1      = (const float*)d_in[2];   // [128]
    const float* alpha   = (const float*)d_in[3];   // [128]
    const float* W2      = (const float*)d_in[4];   // [128,2]
    const float* b2      = (const float*)d_in[5];   // [2]
    const int*   row     = (const int*)d_in[6];     // [1M]
    const int*   col     = (const int*)d_in[7];     // [1M]
    const int*   label   = (const int*)d_in[8];     // [100000]
    float* out = (float*)d_out;

    char* ws = (char*)d_ws;
    unsigned char* PQ8 = (unsigned char*)(ws);      // 25,600,000 B
    float* aux   = (float*)(ws + 25600000);         // 1,600,000 B (float4 slots)
    bf16_t* WT   = (bf16_t*)(ws + 27200000);        // 65,536 B
    float* wabsp = (float*)(ws + 27265536);         // 512 B
    float* w1g   = (float*)(ws + 27266048);         // 512 B
    float* constg= (float*)(ws + 27266560);         // 4 B

    k_prep<<<129, 256, 0, stream>>>(W1, b1, alpha, W2, b2, WT, wabsp, w1g,
                                    constg, out);
    k_gemm<<<6250, 256, 0, stream>>>(feature, WT, b1, w1g, label, PQ8, aux);
    k_edge_loss<<<4096, 256, 0, stream>>>(PQ8, (const float4*)aux, wabsp, constg,
                                          row, col, out);
}

// Round 11
// 192.161 us; speedup vs baseline: 1.1364x; 1.0303x over previous
//
#include <hip/hip_runtime.h>
#include <hip/hip_bf16.h>

typedef __bf16 bf16_t;
typedef bf16_t bf16x8 __attribute__((ext_vector_type(8)));
typedef float floatx4 __attribute__((ext_vector_type(4)));
typedef float floatx2 __attribute__((ext_vector_type(2)));

#define N_NODES 100000
#define N_EDGES 1000000

// PQ4 layout (128 B/node): nibble nb (0..127) of half h holds fp4(e2m1) of
// channel col(nb) = (nb & 64) + (nb & 3)*16 + ((nb >> 2) & 15).
// Gemm wave (h, wq) lane l15 packs nt=0..3 at nb = wq*64 + l15*4 + nt
// (one ushort at byte offset h*64 + wq*32 + l15*2). Edge lane lg reads the
// dword at byte lg*4 of each half = nibbles lg*8..lg*8+7; wabsp indexed by nb.

// ---------------- kernel 1: prep ----------------
__global__ __launch_bounds__(256) void k_prep(const float* __restrict__ W1,
                                              const float* __restrict__ b1,
                                              const float* __restrict__ alpha,
                                              const float* __restrict__ W2,
                                              const float* __restrict__ b2,
                                              bf16_t* __restrict__ WT,
                                              float* __restrict__ wabsp,
                                              float* __restrict__ w1g,
                                              float* __restrict__ constg,
                                              float* __restrict__ out) {
    const int t = threadIdx.x;
    if (blockIdx.x < 128) {
        // WT[n][k] = Wcat[k][n] bf16; Wcat[k,n] = n<128 ? W1[k,n] : W1[k+128,n-128]
        int i = blockIdx.x * 256 + t;
        int n = i >> 7, k = i & 127;
        float v = (n < 128) ? W1[k * 128 + n] : W1[(k + 128) * 128 + (n - 128)];
        WT[i] = (bf16_t)v;
        return;
    }
    __shared__ float w1L[128];
    if (t < 128) {
        float wd = W2[2 * t + 1] - W2[2 * t];
        float al = alpha[t];
        float w1v = wd * (1.f + al) * 0.5f;
        w1L[t] = w1v;
        w1g[t] = w1v;
        int col = (t & 64) + (t & 3) * 16 + ((t >> 2) & 15);   // nibble->channel
        float wdc = W2[2 * col + 1] - W2[2 * col];
        wabsp[t] = wdc * (1.f - alpha[col]) * 0.5f;
    }
    __syncthreads();
    if (t < 64) {   // CONST = sum w1*b1 + (b2[1]-b2[0]), wave-reduced
        float c = fmaf(w1L[t], b1[t], w1L[t + 64] * b1[t + 64]);
#pragma unroll
        for (int m = 32; m >= 1; m >>= 1) c += __shfl_xor(c, m, 64);
        if (t == 0) { *constg = c + (b2[1] - b2[0]); out[0] = 0.f; }
    }
}

// fp32 -> fp4 e2m1 code (RTN boundaries at exact midpoints), sign in bit 3
__device__ inline unsigned fp4_code(float x) {
    float a = fabsf(x);
    unsigned code = (unsigned)(a > 0.25f) + (a > 0.75f) + (a > 1.25f) + (a > 1.75f)
                  + (a > 2.5f) + (a > 3.5f) + (a > 5.0f);
    return code | (x < 0.f ? 8u : 0u);
}

// ---------------- kernel 2: GEMM, dual-half per block (32 rows x 256 cols) -
// A loaded once into regs; WT half staged into 32 KB LDS per phase.
__global__ __launch_bounds__(256) void k_gemm(const float* __restrict__ F,     // [100000,128]
                                              const bf16_t* __restrict__ WT,   // [256,128]
                                              const float* __restrict__ b1,
                                              const float* __restrict__ w1g,
                                              const int* __restrict__ label,
                                              unsigned char* __restrict__ PQ4,
                                              float4* __restrict__ aux_g) {
    __shared__ bf16x8 Bs[2048];          // 32 KB staging
    __shared__ float sP1[4][16];
    __shared__ float sP2[4][16];
    const int t = threadIdx.x;
    const int m0 = blockIdx.x * 32;      // grid 3125 -> exact cover

    const int w = t >> 6, lane = t & 63;
    const int l15 = lane & 15, quad = lane >> 4;
    const int rw = w >> 1, wq = w & 1;

    // A loads (8 dwordx4, issued first)
    const int arow = m0 + rw * 16 + l15;
    const float4* Ar = (const float4*)(F + (size_t)arow * 128 + quad * 8);
    float4 fa[4], fb[4];
#pragma unroll
    for (int s = 0; s < 4; ++s) { fa[s] = Ar[s * 8]; fb[s] = Ar[s * 8 + 1]; }

    float w1v[4], bv[4];
#pragma unroll
    for (int nt = 0; nt < 4; ++nt) {
        int c = wq * 64 + nt * 16 + l15;
        w1v[nt] = w1g[c];
        bv[nt] = b1[c];                  // used in phase 0 only
    }

    // stage B half 0: chunk cc of row c stored at c*16 + (cc ^ (c&15))
    const bf16x8* WT8 = (const bf16x8*)WT;
#pragma unroll
    for (int j = 0; j < 8; ++j) {
        int chunk = j * 256 + t;
        int c = chunk >> 4, cc = chunk & 15;
        Bs[c * 16 + (cc ^ (c & 15))] = WT8[chunk];
    }

    bf16x8 Af[4];
#pragma unroll
    for (int s = 0; s < 4; ++s) {
        bf16x8 v;
        v[0] = (bf16_t)fa[s].x; v[1] = (bf16_t)fa[s].y;
        v[2] = (bf16_t)fa[s].z; v[3] = (bf16_t)fa[s].w;
        v[4] = (bf16_t)fb[s].x; v[5] = (bf16_t)fb[s].y;
        v[6] = (bf16_t)fb[s].z; v[7] = (bf16_t)fb[s].w;
        Af[s] = v;
    }
    __syncthreads();

#pragma unroll
    for (int h = 0; h < 2; ++h) {
        floatx4 acc[4] = {};
#pragma unroll
        for (int s = 0; s < 4; ++s) {
            bf16x8 Bf[4];
#pragma unroll
            for (int nt = 0; nt < 4; ++nt) {
                int c = wq * 64 + nt * 16 + l15;
                Bf[nt] = Bs[c * 16 + ((s * 4 + quad) ^ (c & 15))];
            }
#pragma unroll
            for (int nt = 0; nt < 4; ++nt)
                acc[nt] = __builtin_amdgcn_mfma_f32_16x16x32_bf16(Af[s], Bf[nt], acc[nt], 0, 0, 0);
        }

        // aux partial: sum_nt w1[c]*acc_raw, reduced over l15
#pragma unroll
        for (int r = 0; r < 4; ++r) {
            float sv = 0.f;
#pragma unroll
            for (int nt = 0; nt < 4; ++nt) sv = fmaf(w1v[nt], acc[nt][r], sv);
#pragma unroll
            for (int m = 8; m >= 1; m >>= 1) sv += __shfl_xor(sv, m, 64);
            if (l15 == 0) {
                if (h == 0) sP1[w][quad * 4 + r] = sv;
                else        sP2[w][quad * 4 + r] = sv;
            }
        }

        // epilogue: fp4 pack, ushort store (bias only on half 0)
#pragma unroll
        for (int r = 0; r < 4; ++r) {
            int g = m0 + rw * 16 + quad * 4 + r;
            float v0 = acc[0][r], v1 = acc[1][r], v2 = acc[2][r], v3 = acc[3][r];
            if (h == 0) { v0 += bv[0]; v1 += bv[1]; v2 += bv[2]; v3 += bv[3]; }
            unsigned pk = fp4_code(v0) | (fp4_code(v1) << 4)
                        | (fp4_code(v2) << 8) | (fp4_code(v3) << 12);
            *(unsigned short*)(PQ4 + (size_t)g * 128 + h * 64 + wq * 32 + l15 * 2) =
                (unsigned short)pk;
        }

        // restage B half 1 (barrier: phase-0 LDS reads done before overwrite)
        if (h == 0) {
            __syncthreads();
#pragma unroll
            for (int j = 0; j < 8; ++j) {
                int chunk = j * 256 + t;
                int c = chunk >> 4, cc = chunk & 15;
                Bs[c * 16 + (cc ^ (c & 15))] = WT8[2048 + chunk];
            }
            __syncthreads();
        }
    }

    __syncthreads();
    if (t < 32) {
        int rw2 = t >> 4, ri = t & 15;
        float s1 = sP1[rw2 * 2][ri] + sP1[rw2 * 2 + 1][ri];
        float s2 = sP2[rw2 * 2][ri] + sP2[rw2 * 2 + 1][ri];
        int g = m0 + rw2 * 16 + ri;
        float4 av = {s1, s2, __int_as_float(label[g]), 0.f};
        aux_g[g] = av;
    }
}

// fp4-nibble dword -> two fp8 dwords (even j, odd j) via v_perm LUT
__device__ inline void fp4_decode(unsigned d, unsigned& pe, unsigned& po) {
    unsigned ne = d & 0x0F0F0F0Fu;
    unsigned no = (d >> 4) & 0x0F0F0F0Fu;
    pe = __builtin_amdgcn_perm(0x4C484440u, 0x3C383000u, ne & 0x07070707u)
       | ((ne & 0x08080808u) << 4);
    po = __builtin_amdgcn_perm(0x4C484440u, 0x3C383000u, no & 0x07070707u)
       | ((no & 0x08080808u) << 4);
}

// ---------------- kernel 3: per-edge loss, 16 lanes/edge, 8-edge ILP -------
__global__ __launch_bounds__(256) void k_edge_loss(const unsigned char* __restrict__ PQ4,
                                                   const float4* __restrict__ aux,
                                                   const float* __restrict__ wabsp,
                                                   const float* __restrict__ constg,
                                                   const int* __restrict__ row,
                                                   const int* __restrict__ col,
                                                   float* __restrict__ out) {
    const int lg = threadIdx.x & 15;
    const int group = (blockIdx.x * blockDim.x + threadIdx.x) >> 4;
    const int ng = (gridDim.x * blockDim.x) >> 4;

    // wabs register order: even j {0,2,4,6} then odd {1,3,5,7} (decode order)
    float wabs[8];
    const float* wb = wabsp + lg * 8;
    wabs[0] = wb[0]; wabs[1] = wb[2]; wabs[2] = wb[4]; wabs[3] = wb[6];
    wabs[4] = wb[1]; wabs[5] = wb[3]; wabs[6] = wb[5]; wabs[7] = wb[7];
    const float CB = *constg;

    float acc = 0.f;
    for (int e = group; e < N_EDGES; e += 8 * ng) {
        int r[8], c[8];
#pragma unroll
        for (int k = 0; k < 8; ++k) {
            int ee = e + k * ng;
            int es = (ee < N_EDGES) ? ee : e;
            r[k] = row[es]; c[k] = col[es];
        }
        unsigned p[8], q[8];
#pragma unroll
        for (int k = 0; k < 8; ++k) {
            p[k] = *(const unsigned*)(PQ4 + (size_t)r[k] * 128 + lg * 4);
            q[k] = *(const unsigned*)(PQ4 + (size_t)c[k] * 128 + 64 + lg * 4);
        }
        int ee2 = e + (lg & 7) * ng;
        int es2 = (ee2 < N_EDGES) ? ee2 : e;
        const int* ibase = (lg < 8) ? row : col;
        float4 a = aux[ibase[es2]];

        float sab[8] = {0.f, 0.f, 0.f, 0.f, 0.f, 0.f, 0.f, 0.f};
#pragma unroll
        for (int k = 0; k < 8; ++k) {
            unsigned pe, po, qe, qo;
            fp4_decode(p[k], pe, po);
            fp4_decode(q[k], qe, qo);
            floatx2 he0 = __builtin_amdgcn_cvt_pk_f32_fp8((int)pe, false)
                        + __builtin_amdgcn_cvt_pk_f32_fp8((int)qe, false);   // j0,j2
            floatx2 he1 = __builtin_amdgcn_cvt_pk_f32_fp8((int)pe, true)
                        + __builtin_amdgcn_cvt_pk_f32_fp8((int)qe, true);    // j4,j6
            floatx2 ho0 = __builtin_amdgcn_cvt_pk_f32_fp8((int)po, false)
                        + __builtin_amdgcn_cvt_pk_f32_fp8((int)qo, false);   // j1,j3
            floatx2 ho1 = __builtin_amdgcn_cvt_pk_f32_fp8((int)po, true)
                        + __builtin_amdgcn_cvt_pk_f32_fp8((int)qo, true);    // j5,j7
            float s = sab[k];
            s = fmaf(fabsf(he0[0]), wabs[0], s);
            s = fmaf(fabsf(he0[1]), wabs[1], s);
            s = fmaf(fabsf(he1[0]), wabs[2], s);
            s = fmaf(fabsf(he1[1]), wabs[3], s);
            s = fmaf(fabsf(ho0[0]), wabs[4], s);
            s = fmaf(fabsf(ho0[1]), wabs[5], s);
            s = fmaf(fabsf(ho1[0]), wabs[6], s);
            s = fmaf(fabsf(ho1[1]), wabs[7], s);
            sab[k] = s;
        }
#pragma unroll
        for (int m = 8; m >= 1; m >>= 1) {
#pragma unroll
            for (int k = 0; k < 8; ++k) sab[k] += __shfl_xor(sab[k], m, 16);
        }
        float s2o = __shfl(a.y, (lg + 8) & 15, 16);
        float lzc = __shfl(a.z, (lg + 8) & 15, 16);
        float mysab = sab[0];
#pragma unroll
        for (int k = 1; k < 8; ++k) mysab = (lg == k) ? sab[k] : mysab;
        float D = a.x + s2o + CB + mysab;
        float sgn = (__float_as_int(a.z) == __float_as_int(lzc)) ? -D : D;
        float loss = fmaxf(sgn, 0.f) + __logf(1.f + __expf(-fabsf(sgn)));
        bool vld = (lg < 8) && (e + lg * ng < N_EDGES);
        acc += vld ? loss : 0.f;
    }
#pragma unroll
    for (int m = 32; m >= 1; m >>= 1) acc += __shfl_xor(acc, m, 64);
    __shared__ float sdata[4];
    int lane = threadIdx.x & 63;
    int wv = threadIdx.x >> 6;
    if (lane == 0) sdata[wv] = acc;
    __syncthreads();
    if (threadIdx.x == 0) {
        float s = (sdata[0] + sdata[1]) + (sdata[2] + sdata[3]);
        atomicAdd(out, s * (1.f / (float)N_EDGES));
    }
}

extern "C" void kernel_launch(void* const* d_in, const int* in_sizes, int n_in,
                              void* d_out, int out_size, void* d_ws, size_t ws_size,
                              hipStream_t stream) {
    const float* feature = (const float*)d_in[0];   // [100000,128]
    const float* W1      = (const float*)d_in[1];   // [256,128]
    const float* b1      = (const float*)d_in[2];   // [128]
    const float* alpha   = (const float*)d_in[3];   // [128]
    const float* W2      = (const float*)d_in[4];   // [128,2]
    const float* b2      = (const float*)d_in[5];   // [2]
    const int*   row     = (const int*)d_in[6];     // [1M]
    const int*   col     = (const int*)d_in[7];     // [1M]
    const int*   label   = (const int*)d_in[8];     // [100000]
    float* out = (float*)d_out;

    char* ws = (char*)d_ws;
    unsigned char* PQ4 = (unsigned char*)(ws);      // 12,800,000 B
    float* aux   = (float*)(ws + 12800000);         // 1,600,000 B (float4 slots)
    bf16_t* WT   = (bf16_t*)(ws + 14400000);        // 65,536 B
    float* wabsp = (float*)(ws + 14465536);         // 512 B
    float* w1g   = (float*)(ws + 14466048);         // 512 B
    float* constg= (float*)(ws + 14466560);         // 4 B

    k_prep<<<129, 256, 0, stream>>>(W1, b1, alpha, W2, b2, WT, wabsp, w1g,
                                    constg, out);
    k_gemm<<<3125, 256, 0, stream>>>(feature, WT, b1, w1g, label, PQ4,
                                     (float4*)aux);
    k_edge_loss<<<4096, 256, 0, stream>>>(PQ4, (const float4*)aux, wabsp, constg,
                                          row, col, out);
}